// Round 6
// baseline (1060.741 us; speedup 1.0000x reference)
//
#include <hip/hip_runtime.h>
#include <math.h>

#define NN   50000
#define TT   2
#define CC   768
#define GG   16
#define EE   800000
#define HH   192
#define OUTD 3
#define MR   (NN*TT)   // 100000 rows
#define FD   (TT*HH)   // 384 features per node
#define EPS_GN 1e-5f
#define GN_CHUNK 32

typedef __attribute__((ext_vector_type(8))) short bf16x8;
typedef __attribute__((ext_vector_type(4))) float f32x4;

__device__ __forceinline__ float gelu_exact(float x){
    return 0.5f * x * (1.0f + erff(x * 0.70710678118654752440f));
}

__device__ __forceinline__ short f2b(float f){   // RNE float->bf16
    unsigned u = __float_as_uint(f);
    unsigned r = (u + 0x7FFFu + ((u>>16)&1u)) >> 16;
    return (short)r;
}
__device__ __forceinline__ float b2f(unsigned short u){
    return __uint_as_float(((unsigned)u)<<16);
}

// ---------- degree ----------
__global__ __launch_bounds__(256) void k_deg(const int* __restrict__ dst, float* __restrict__ deg){
    int e = blockIdx.x*256 + threadIdx.x;
    if(e < EE) atomicAdd(&deg[dst[e]], 1.0f);
}

// ---------- weight convert: W[K][192] fp32 -> Wt[192][K] bf16 ----------
__global__ __launch_bounds__(256) void k_wconv(const float* __restrict__ W0, const float* __restrict__ W1,
                                               const float* __restrict__ Wh1,
                                               short* __restrict__ Wt0, short* __restrict__ Wt1,
                                               short* __restrict__ Wth1){
    int i = blockIdx.x*256 + threadIdx.x;
    if(i < CC*HH){
        int k = i / HH, n = i % HH;
        Wt0[(size_t)n*CC + k] = f2b(W0[i]);
    }
    if(i < HH*HH){
        int k = i / HH, n = i % HH;
        Wt1 [(size_t)n*HH + k] = f2b(W1[i]);
        Wth1[(size_t)n*HH + k] = f2b(Wh1[i]);
    }
}

// ---------- CSR build (scan1 also emits dinv; scan2 also emits cnt) ----------
__global__ __launch_bounds__(256) void k_scan1(const float* __restrict__ deg, int* __restrict__ partial,
                                               float* __restrict__ dinv){
    __shared__ int s[256];
    int t = threadIdx.x;
    int i = blockIdx.x*256 + t;
    float dv = (i < NN) ? deg[i] : 0.f;
    if(i < NN) dinv[i] = rsqrtf(dv + 1.0f);
    int v = (int)dv;
    s[t] = v; __syncthreads();
    for(int off=128; off>0; off>>=1){ if(t < off) s[t] += s[t+off]; __syncthreads(); }
    if(t == 0) partial[blockIdx.x] = s[0];
}

__global__ __launch_bounds__(256) void k_scan2(int* __restrict__ partial, const int* __restrict__ batch,
                                               float* __restrict__ cnt){
    __shared__ int s[256];
    int t = threadIdx.x;
    if(t < GG){   // fused group-count (batch is sorted)
        int g = t;
        int lo0=0, hi=NN;
        while(lo0<hi){ int mid=(lo0+hi)>>1; if(batch[mid] < g) lo0=mid+1; else hi=mid; }
        int lo1=lo0; hi=NN;
        while(lo1<hi){ int mid=(lo1+hi)>>1; if(batch[mid] < g+1) lo1=mid+1; else hi=mid; }
        cnt[g] = (float)(lo1 - lo0);
    }
    int v = partial[t];
    s[t] = v; __syncthreads();
    for(int off=1; off<256; off<<=1){
        int x = (t >= off) ? s[t-off] : 0;
        __syncthreads();
        s[t] += x;
        __syncthreads();
    }
    partial[t] = s[t] - v;
}

__global__ __launch_bounds__(256) void k_scan3(const float* __restrict__ deg, const int* __restrict__ partial,
                                               int* __restrict__ csr_off){
    __shared__ int s[256];
    int t = threadIdx.x;
    int i = blockIdx.x*256 + t;
    int v = (i < NN) ? (int)deg[i] : 0;
    s[t] = v; __syncthreads();
    for(int off=1; off<256; off<<=1){
        int x = (t >= off) ? s[t-off] : 0;
        __syncthreads();
        s[t] += x;
        __syncthreads();
    }
    if(i < NN) csr_off[i] = partial[blockIdx.x] + s[t] - v;
}

__global__ __launch_bounds__(256) void k_fill(const int* __restrict__ src, const int* __restrict__ dst,
                                              const int* __restrict__ csr_off, int* __restrict__ fillcnt,
                                              int* __restrict__ csr_src){
    int e = blockIdx.x*256 + threadIdx.x;
    if(e < EE){
        int d = dst[e];
        int pos = csr_off[d] + atomicAdd(&fillcnt[d], 1);
        csr_src[pos] = src[e];
    }
}

// ---------- GEMM0: K=768, LDS double-staged A and B, 2-phase register prefetch ----------
__global__ __launch_bounds__(256) void k_gemm0(const float* __restrict__ A, const short* __restrict__ Bt,
                                               short* __restrict__ C, int Mrows){
    __shared__ short As[64][40];
    __shared__ short Bs[192][40];
    int tid = threadIdx.x;
    int bm = blockIdx.x*64;
    int wv = tid>>6, lane = tid&63;
    int lm = lane&15, lq = lane>>4;

    f32x4 acc[12];
    #pragma unroll
    for(int i=0;i<12;i++) acc[i] = (f32x4){0.f,0.f,0.f,0.f};

    int ar = tid>>2, akg = (tid&3)<<3;
    int row = bm + ar;
    bool aok = row < Mrows;
    const float* Ap = A + (size_t)row*CC + akg;

    float4 ra0 = make_float4(0,0,0,0), ra1 = ra0;
    bf16x8 bv[3];
    if(aok){ ra0 = *(const float4*)(Ap); ra1 = *(const float4*)(Ap + 4); }
    #pragma unroll
    for(int i=0;i<3;i++){
        int idx = tid + i*256;
        int n = idx>>2, kg = (idx&3)<<3;
        bv[i] = *(const bf16x8*)(Bt + (size_t)n*CC + kg);
    }

    for(int k0 = 0; k0 < CC; k0 += 32){
        bf16x8 ap = {};
        if(aok){
            ap[0]=f2b(ra0.x); ap[1]=f2b(ra0.y); ap[2]=f2b(ra0.z); ap[3]=f2b(ra0.w);
            ap[4]=f2b(ra1.x); ap[5]=f2b(ra1.y); ap[6]=f2b(ra1.z); ap[7]=f2b(ra1.w);
        }
        bf16x8 bw0 = bv[0], bw1 = bv[1], bw2 = bv[2];
        __syncthreads();
        *(bf16x8*)&As[ar][akg] = ap;
        {
            int idx0 = tid, idx1 = tid+256, idx2 = tid+512;
            *(bf16x8*)&Bs[idx0>>2][(idx0&3)<<3] = bw0;
            *(bf16x8*)&Bs[idx1>>2][(idx1&3)<<3] = bw1;
            *(bf16x8*)&Bs[idx2>>2][(idx2&3)<<3] = bw2;
        }
        __syncthreads();
        int k1 = k0 + 32;
        if(k1 < CC){
            if(aok){ ra0 = *(const float4*)(Ap + k1); ra1 = *(const float4*)(Ap + k1 + 4); }
            #pragma unroll
            for(int i=0;i<3;i++){
                int idx = tid + i*256;
                int n = idx>>2, kg = (idx&3)<<3;
                bv[i] = *(const bf16x8*)(Bt + (size_t)n*CC + k1 + kg);
            }
        }
        bf16x8 af = *(const bf16x8*)&As[wv*16 + lm][lq*8];
        #pragma unroll
        for(int ct=0; ct<12; ct++){
            bf16x8 bfr = *(const bf16x8*)&Bs[ct*16 + lm][lq*8];
            acc[ct] = __builtin_amdgcn_mfma_f32_16x16x32_bf16(af, bfr, acc[ct], 0, 0, 0);
        }
    }

    #pragma unroll
    for(int ct=0; ct<12; ct++){
        int col = ct*16 + lm;
        #pragma unroll
        for(int r=0; r<4; r++){
            int orow = bm + wv*16 + lq*4 + r;
            if(orow < Mrows) C[(size_t)orow*HH + col] = f2b(acc[ct][r]);
        }
    }
}

// ---------- GraphNorm affine precompute: gn(x) = kA*x + kB per (g,f) ----------
__global__ __launch_bounds__(256) void k_gnaff(const float* __restrict__ sm, const float* __restrict__ sq,
                                               const float* __restrict__ cnt,
                                               const float* __restrict__ w, const float* __restrict__ b,
                                               const float* __restrict__ a,
                                               float* __restrict__ kA, float* __restrict__ kB){
    int i = blockIdx.x*256 + threadIdx.x;
    if(i < GG*FD){
        int g = i / FD, f = i % FD;
        int hh = (f < HH) ? f : f - HH;
        float ic = 1.0f / cnt[g];
        float mean = sm[i]*ic, ex2 = sq[i]*ic;
        float al = a[hh];
        float var = ex2 - (2.0f*al - al*al)*mean*mean;
        float rs = rsqrtf(var + EPS_GN);
        float ka = w[hh]*rs;
        kA[i] = ka;
        kB[i] = b[hh] - ka*(al*mean);
    }
}

// ---------- K=192 GEMM: one-shot fused A staging (gn+gelu), B direct from L2 ----------
// MODE 1: C = bf16(A@Bt^T).  MODE 2: out[M][3] = gelu(A@Bt^T + bias) @ W2 + b2
// NORM 1: A = gelu(kA1*A1 + kB1).  NORM 2: + gelu(kA0*A0 + kB0)
template<int MODE, int NORM>
__global__ __launch_bounds__(256) void k_gemmL(
        const float* __restrict__ A1, const float* __restrict__ A0,
        const short* __restrict__ Bt,
        const float* __restrict__ bias, void* __restrict__ Cv,
        const float* __restrict__ W2, const float* __restrict__ b2,
        const int* __restrict__ batch,
        const float* __restrict__ kA1, const float* __restrict__ kB1,
        const float* __restrict__ kA0, const float* __restrict__ kB0,
        int Mrows){
    __shared__ short As[64][200];   // 64 rows x 192 cols (+8 pad), 25.6 KB
    int tid = threadIdx.x;
    int bm = blockIdx.x*64;

    // ---- one-time cooperative A staging: 4 threads per row, 48 cols each ----
    {
        int ar = tid>>2, cg = tid&3;
        int row = bm + ar;
        if(row < Mrows){
            int g = batch[row>>1];
            int tT = row&1;
            int pb = g*FD + tT*HH;
            const float* a1p  = A1  + (size_t)row*HH;
            const float* ka1p = kA1 + pb;
            const float* kb1p = kB1 + pb;
            const float* a0p  = (NORM==2) ? (A0  + (size_t)row*HH) : a1p;
            const float* ka0p = (NORM==2) ? (kA0 + pb) : ka1p;
            const float* kb0p = (NORM==2) ? (kB0 + pb) : kb1p;
            #pragma unroll
            for(int q=0; q<6; q++){
                int c = cg*48 + q*8;
                float4 u0 = *(const float4*)(a1p+c),  u1 = *(const float4*)(a1p+c+4);
                float4 p0 = *(const float4*)(ka1p+c), p1 = *(const float4*)(ka1p+c+4);
                float4 r0 = *(const float4*)(kb1p+c), r1 = *(const float4*)(kb1p+c+4);
                float uu[8]={u0.x,u0.y,u0.z,u0.w,u1.x,u1.y,u1.z,u1.w};
                float pp[8]={p0.x,p0.y,p0.z,p0.w,p1.x,p1.y,p1.z,p1.w};
                float rr[8]={r0.x,r0.y,r0.z,r0.w,r1.x,r1.y,r1.z,r1.w};
                float v[8];
                #pragma unroll
                for(int j=0;j<8;j++) v[j] = gelu_exact(pp[j]*uu[j] + rr[j]);
                if(NORM==2){
                    float4 w0 = *(const float4*)(a0p+c),  w1 = *(const float4*)(a0p+c+4);
                    float4 s0 = *(const float4*)(ka0p+c), s1 = *(const float4*)(ka0p+c+4);
                    float4 t0 = *(const float4*)(kb0p+c), t1 = *(const float4*)(kb0p+c+4);
                    float ww[8]={w0.x,w0.y,w0.z,w0.w,w1.x,w1.y,w1.z,w1.w};
                    float ss[8]={s0.x,s0.y,s0.z,s0.w,s1.x,s1.y,s1.z,s1.w};
                    float tt[8]={t0.x,t0.y,t0.z,t0.w,t1.x,t1.y,t1.z,t1.w};
                    #pragma unroll
                    for(int j=0;j<8;j++) v[j] += gelu_exact(ss[j]*ww[j] + tt[j]);
                }
                bf16x8 ap;
                #pragma unroll
                for(int j=0;j<8;j++) ap[j] = f2b(v[j]);
                *(bf16x8*)&As[ar][c] = ap;
            }
        } else {
            bf16x8 z = {};
            #pragma unroll
            for(int q=0;q<6;q++) *(bf16x8*)&As[ar][cg*48 + q*8] = z;
        }
    }
    __syncthreads();

    // ---- K-loop: A fragments from LDS, B fragments direct from global (L2-hot) ----
    int wv = tid>>6, lane = tid&63;
    int lm = lane&15, lq = lane>>4;
    f32x4 acc[12];
    #pragma unroll
    for(int i=0;i<12;i++) acc[i] = (f32x4){0.f,0.f,0.f,0.f};

    #pragma unroll
    for(int ks=0; ks<6; ks++){
        int k0 = ks*32;
        bf16x8 af = *(const bf16x8*)&As[wv*16 + lm][k0 + lq*8];
        #pragma unroll
        for(int ct=0; ct<12; ct++){
            bf16x8 bfr = *(const bf16x8*)(Bt + (size_t)(ct*16 + lm)*HH + k0 + lq*8);
            acc[ct] = __builtin_amdgcn_mfma_f32_16x16x32_bf16(af, bfr, acc[ct], 0, 0, 0);
        }
    }

    if(MODE == 1){
        short* C = (short*)Cv;
        #pragma unroll
        for(int ct=0; ct<12; ct++){
            int col = ct*16 + lm;
            #pragma unroll
            for(int r=0; r<4; r++){
                int orow = bm + wv*16 + lq*4 + r;
                if(orow < Mrows) C[(size_t)orow*HH + col] = f2b(acc[ct][r]);
            }
        }
    } else {  // MODE 2: fused head
        float hs[4][3] = {};
        #pragma unroll
        for(int ct=0; ct<12; ct++){
            int col = ct*16 + lm;
            float bs = bias[col];
            float w20 = W2[col*3+0], w21 = W2[col*3+1], w22 = W2[col*3+2];
            #pragma unroll
            for(int r=0; r<4; r++){
                float gl = gelu_exact(acc[ct][r] + bs);
                hs[r][0] += gl*w20; hs[r][1] += gl*w21; hs[r][2] += gl*w22;
            }
        }
        #pragma unroll
        for(int off=1; off<16; off<<=1){
            #pragma unroll
            for(int r=0;r<4;r++){
                hs[r][0] += __shfl_xor(hs[r][0], off);
                hs[r][1] += __shfl_xor(hs[r][1], off);
                hs[r][2] += __shfl_xor(hs[r][2], off);
            }
        }
        if(lm == 0){
            float* O = (float*)Cv;
            #pragma unroll
            for(int r=0;r<4;r++){
                int orow = bm + wv*16 + lq*4 + r;
                if(orow < Mrows){
                    O[(size_t)orow*3+0] = hs[r][0] + b2[0];
                    O[(size_t)orow*3+1] = hs[r][1] + b2[1];
                    O[(size_t)orow*3+2] = hs[r][2] + b2[2];
                }
            }
        }
    }
}

// ---------- GCN aggregation: wave-per-node, no LDS, shfl-broadcast indices ----------
__global__ __launch_bounds__(256) void k_agg(const ushort* __restrict__ hw, const int* __restrict__ csr_src,
                                             const int* __restrict__ csr_off, const float* __restrict__ deg,
                                             const float* __restrict__ dinv, const float* __restrict__ bias,
                                             float* __restrict__ out){
    int lane = threadIdx.x & 63;
    int n = blockIdx.x*4 + (threadIdx.x>>6);
    if(n >= NN) return;
    float di = dinv[n];
    const ushort2* H2 = (const ushort2*)hw;
    size_t rb = (size_t)n*192 + lane*3;       // lane covers ushort2 slots lane*3 .. +2
    ushort2 s0v = H2[rb], s1v = H2[rb+1], s2v = H2[rb+2];
    float self = di*di;
    float a0 = b2f(s0v.x)*self, a1 = b2f(s0v.y)*self;
    float a2 = b2f(s1v.x)*self, a3 = b2f(s1v.y)*self;
    float a4 = b2f(s2v.x)*self, a5 = b2f(s2v.y)*self;
    int beg = csr_off[n];
    int end = beg + (int)deg[n];
    for(int base = beg; base < end; base += 64){
        int m = min(64, end - base);
        int e = 0; float we = 0.f;
        if(lane < m){ e = csr_src[base + lane]; we = dinv[e]*di; }
        int j = 0;
        for(; j+4 <= m; j += 4){
            int   sA=__shfl(e,j),  sB=__shfl(e,j+1),  sC=__shfl(e,j+2),  sD=__shfl(e,j+3);
            float wA=__shfl(we,j), wB=__shfl(we,j+1), wC=__shfl(we,j+2), wD=__shfl(we,j+3);
            size_t bA=(size_t)sA*192+lane*3, bB=(size_t)sB*192+lane*3;
            size_t bC=(size_t)sC*192+lane*3, bD=(size_t)sD*192+lane*3;
            ushort2 vA0=H2[bA], vA1=H2[bA+1], vA2=H2[bA+2];
            ushort2 vB0=H2[bB], vB1=H2[bB+1], vB2=H2[bB+2];
            ushort2 vC0=H2[bC], vC1=H2[bC+1], vC2=H2[bC+2];
            ushort2 vD0=H2[bD], vD1=H2[bD+1], vD2=H2[bD+2];
            a0 += wA*b2f(vA0.x)+wB*b2f(vB0.x)+wC*b2f(vC0.x)+wD*b2f(vD0.x);
            a1 += wA*b2f(vA0.y)+wB*b2f(vB0.y)+wC*b2f(vC0.y)+wD*b2f(vD0.y);
            a2 += wA*b2f(vA1.x)+wB*b2f(vB1.x)+wC*b2f(vC1.x)+wD*b2f(vD1.x);
            a3 += wA*b2f(vA1.y)+wB*b2f(vB1.y)+wC*b2f(vC1.y)+wD*b2f(vD1.y);
            a4 += wA*b2f(vA2.x)+wB*b2f(vB2.x)+wC*b2f(vC2.x)+wD*b2f(vD2.x);
            a5 += wA*b2f(vA2.y)+wB*b2f(vB2.y)+wC*b2f(vC2.y)+wD*b2f(vD2.y);
        }
        for(; j < m; j++){
            int s = __shfl(e, j); float ww = __shfl(we, j);
            size_t sb = (size_t)s*192 + lane*3;
            ushort2 v0=H2[sb], v1=H2[sb+1], v2=H2[sb+2];
            a0 += ww*b2f(v0.x); a1 += ww*b2f(v0.y);
            a2 += ww*b2f(v1.x); a3 += ww*b2f(v1.y);
            a4 += ww*b2f(v2.x); a5 += ww*b2f(v2.y);
        }
    }
    int f0 = lane*6;
    float r[6] = {a0,a1,a2,a3,a4,a5};
    float* O = out + (size_t)n*FD + f0;
    #pragma unroll
    for(int i=0;i<6;i++){
        int f = f0 + i;
        int hh = (f < HH) ? f : f - HH;
        O[i] = r[i] + bias[hh];
    }
}

// ---------- GraphNorm stats: quad-preload, sorted-batch fast path ----------
__global__ __launch_bounds__(384) void k_gn_stats(const float* __restrict__ h, const int* __restrict__ batch,
                                                  float* __restrict__ ssum, float* __restrict__ ssq){
    int f = threadIdx.x;
    int n0 = blockIdx.x*GN_CHUNK;
    int n1 = min(n0 + GN_CHUNK, NN);
    int g = batch[n0];
    float a = 0.f, a2 = 0.f;
    int n = n0;
    for(; n+4 <= n1; n += 4){
        float v0 = h[(size_t)n*FD + f];
        float v1 = h[(size_t)(n+1)*FD + f];
        float v2 = h[(size_t)(n+2)*FD + f];
        float v3 = h[(size_t)(n+3)*FD + f];
        int b3 = batch[n+3];
        if(b3 == g){   // sorted => all four rows in run g
            a  += v0+v1+v2+v3;
            a2 += v0*v0+v1*v1+v2*v2+v3*v3;
        } else {
            float vv[4] = {v0,v1,v2,v3};
            #pragma unroll
            for(int q=0;q<4;q++){
                int gn = batch[n+q];
                if(gn != g){
                    atomicAdd(&ssum[g*FD + f], a);
                    atomicAdd(&ssq [g*FD + f], a2);
                    a = 0.f; a2 = 0.f; g = gn;
                }
                a += vv[q]; a2 += vv[q]*vv[q];
            }
        }
    }
    for(; n < n1; n++){
        int gn = batch[n];
        if(gn != g){
            atomicAdd(&ssum[g*FD + f], a);
            atomicAdd(&ssq [g*FD + f], a2);
            a = 0.f; a2 = 0.f; g = gn;
        }
        float v = h[(size_t)n*FD + f];
        a += v; a2 += v*v;
    }
    atomicAdd(&ssum[g*FD + f], a);
    atomicAdd(&ssq [g*FD + f], a2);
}

extern "C" void kernel_launch(void* const* d_in, const int* in_sizes, int n_in,
                              void* d_out, int out_size, void* d_ws, size_t ws_size,
                              hipStream_t stream){
    const float* x     = (const float*)d_in[0];
    const int*   batch = (const int*)d_in[1];
    const int*   ei    = (const int*)d_in[2];
    const int*   src   = ei;
    const int*   dst   = ei + EE;
    const float* W0    = (const float*)d_in[3];
    const float* b0    = (const float*)d_in[4];
    const float* gn0_w = (const float*)d_in[5];
    const float* gn0_b = (const float*)d_in[6];
    const float* gn0_a = (const float*)d_in[7];
    const float* W1    = (const float*)d_in[8];
    const float* b1    = (const float*)d_in[9];
    const float* gn1_w = (const float*)d_in[10];
    const float* gn1_b = (const float*)d_in[11];
    const float* gn1_a = (const float*)d_in[12];
    const float* Wh1   = (const float*)d_in[13];
    const float* bh1   = (const float*)d_in[14];
    const float* Wh2   = (const float*)d_in[15];
    const float* bh2   = (const float*)d_in[16];
    float* out = (float*)d_out;

    char* w = (char*)d_ws;
    auto alloc = [&](size_t bytes)->void*{
        void* p = (void*)w;
        w += (bytes + 255) & ~(size_t)255;
        return p;
    };
    char* zbase = w;
    float* deg     = (float*)alloc((size_t)NN*4);
    int*   fillcnt = (int*)  alloc((size_t)NN*4);
    int*   partial = (int*)  alloc(256*4);
    float* s0m     = (float*)alloc((size_t)GG*FD*4);
    float* s0q     = (float*)alloc((size_t)GG*FD*4);
    float* s1m     = (float*)alloc((size_t)GG*FD*4);
    float* s1q     = (float*)alloc((size_t)GG*FD*4);
    size_t zbytes = (size_t)(w - zbase);
    float* cnt     = (float*)alloc((size_t)GG*4);
    float* dinv    = (float*)alloc((size_t)NN*4);
    int*   csr_off = (int*)  alloc((size_t)NN*4);
    int*   csr_src = (int*)  alloc((size_t)EE*4);
    float* k0A     = (float*)alloc((size_t)GG*FD*4);
    float* k0B     = (float*)alloc((size_t)GG*FD*4);
    float* k1A     = (float*)alloc((size_t)GG*FD*4);
    float* k1B     = (float*)alloc((size_t)GG*FD*4);
    short* Wt0     = (short*)alloc((size_t)HH*CC*2);
    short* Wt1     = (short*)alloc((size_t)HH*HH*2);
    short* Wth1    = (short*)alloc((size_t)HH*HH*2);
    short* hb0     = (short*)alloc((size_t)MR*HH*2);   // bf16 GEMM0 output (agg0 input)
    short* hb1     = (short*)alloc((size_t)MR*HH*2);   // bf16 GEMM1 output (agg1 input)
    float* agg0    = (float*)alloc((size_t)MR*HH*4);   // fp32 pre-norm layer0 (kept for residual)
    float* agg1    = (float*)alloc((size_t)MR*HH*4);   // fp32 pre-norm layer1

    hipMemsetAsync(zbase, 0, zbytes, stream);

    k_deg  <<<(EE+255)/256, 256, 0, stream>>>(dst, deg);
    k_wconv<<<(CC*HH+255)/256, 256, 0, stream>>>(W0, W1, Wh1, Wt0, Wt1, Wth1);

    int nscan = (NN+255)/256;
    k_scan1<<<nscan, 256, 0, stream>>>(deg, partial, dinv);
    k_scan2<<<1,     256, 0, stream>>>(partial, batch, cnt);
    k_scan3<<<nscan, 256, 0, stream>>>(deg, partial, csr_off);
    k_fill <<<(EE+255)/256, 256, 0, stream>>>(src, dst, csr_off, fillcnt, csr_src);

    int gemm_grid = (MR+63)/64;
    int agg_grid  = (NN+3)/4;
    int ngn  = (NN + GN_CHUNK - 1)/GN_CHUNK;
    int naff = (GG*FD + 255)/256;

    // layer 0: 768 -> 192 (raw fp32 A = x)
    k_gemm0<<<gemm_grid, 256, 0, stream>>>(x, Wt0, hb0, MR);
    k_agg<<<agg_grid, 256, 0, stream>>>((const ushort*)hb0, csr_src, csr_off, deg, dinv, b0, agg0);
    k_gn_stats<<<ngn, 384, 0, stream>>>(agg0, batch, s0m, s0q);
    k_gnaff<<<naff, 256, 0, stream>>>(s0m, s0q, cnt, gn0_w, gn0_b, gn0_a, k0A, k0B);

    // layer 1: A = gelu(gn0(agg0)) fused into one-shot A staging; 192 -> 192
    k_gemmL<1,1><<<gemm_grid, 256, 0, stream>>>(
        agg0, nullptr, Wt1, nullptr, hb1, nullptr, nullptr,
        batch, k0A, k0B, nullptr, nullptr, MR);
    k_agg<<<agg_grid, 256, 0, stream>>>((const ushort*)hb1, csr_src, csr_off, deg, dinv, b1, agg1);
    k_gn_stats<<<ngn, 384, 0, stream>>>(agg1, batch, s1m, s1q);
    k_gnaff<<<naff, 256, 0, stream>>>(s1m, s1q, cnt, gn1_w, gn1_b, gn1_a, k1A, k1B);

    // fused head: A = gelu(gn1(agg1)) + gelu(gn0(agg0)); out = gelu(A@Wh1+bh1)@Wh2+bh2
    k_gemmL<2,2><<<gemm_grid, 256, 0, stream>>>(
        agg1, agg0, Wth1, bh1, out, Wh2, bh2,
        batch, k1A, k1B, k0A, k0B, MR);
}